// Round 3
// baseline (35.796 us; speedup 1.0000x reference)
//
#include <hip/hip_runtime.h>

// ---------------------------------------------------------------------------
// TimeLSTMCell fused kernel for MI355X (gfx950) — round 5
// B=4096, D=256, U=512; out = concat(h, c_m) fp32
//
// prep kernel (UNCHANGED since r2): x,h0 -> bf16 swizzled 128x64 tiles;
//   kernel,rk -> transposed bf16 swizzled {160,96}x64 tiles. Main kernel
//   stages with linear global_load_lds and reads with the XOR swizzle.
//
// ROUND 5 CHANGES (r3 XCD remap neutral, r4 LDS-read cut neutral -> the
// binding cost is the per-step vmcnt(0) drain of __syncthreads + staging
// re-read volume):
//  1. T3/T4 counted-vmcnt pipeline: raw s_barrier + s_waitcnt vmcnt(N),
//     N = next tile's in-flight loads (never 0 until the last step). The
//     prefetch for tile s+1 now has a full step to land instead of being
//     drained at the end of the step that issued it.
//  2. Block widened to 128x64 (512 thr / 8 waves, 2x4 wave grid of 64r x
//     16c). Staging total 193 -> 142 MB (A re-read 16x -> 8x). B-tiles:
//     two 32-col prep tiles stacked in LDS, so prep is untouched.
//     acc stays 128 VGPR/thread; LDS 2 x 56KB = 112KB, 1 block/CU.
//  3. c0 prefetched into 16 VGPRs at step 8 (asm-fence pinned; vmcnt
//     constants account for it) -> removes 8MB HBM read from the tail.
// ---------------------------------------------------------------------------

typedef __attribute__((ext_vector_type(8))) short short8_t;   // 8 bf16
typedef __attribute__((ext_vector_type(4))) float f32x4_t;
typedef unsigned int u32;

#define B_N 4096
#define D_K 256
#define U_N 512

__device__ __forceinline__ unsigned short f2bf(float f) {
    unsigned int x = __float_as_uint(f);
    unsigned int r = x + 0x7fffu + ((x >> 16) & 1u);   // RNE
    return (unsigned short)(r >> 16);
}

__device__ __forceinline__ float sigf(float z) {
    return 1.0f / (1.0f + __expf(-z));
}

// fast tanh: exact at +/-inf, ~1e-7 abs err
__device__ __forceinline__ float tanhfast(float z) {
    return 1.0f - 2.0f / (1.0f + __expf(2.0f * z));
}

__device__ __forceinline__ void gl16(const unsigned short* g, unsigned short* l) {
    __builtin_amdgcn_global_load_lds(
        (const __attribute__((address_space(1))) u32*)g,
        (__attribute__((address_space(3))) u32*)l, 16, 0, 0);
}

// swizzled element offset of (row r, k-chunk kc) inside a tile with 8 chunks/row
#define SWZ(r, kc) ((((r) * 8) + ((kc) ^ ((r) & 7))) * 8)

// counted vmcnt wait + scheduling fence (compile-time literal N)
#define WAIT_VM(N)                                            \
    asm volatile("s_waitcnt vmcnt(" #N ")" ::: "memory");     \
    __builtin_amdgcn_sched_barrier(0)

// ---------------------------------------------------------------------------
// prepass (unchanged): 4 segments by flat chunk id (16B bf16 chunk each)
// ---------------------------------------------------------------------------
__global__ __launch_bounds__(256) void prep(
    const float* __restrict__ x, const float* __restrict__ h0,
    const float* __restrict__ kern, const float* __restrict__ rk,
    unsigned short* __restrict__ xs, unsigned short* __restrict__ hs,
    unsigned short* __restrict__ ksw, unsigned short* __restrict__ rsw)
{
    const int c = blockIdx.x * 256 + threadIdx.x;
    if (c < 131072) {                       // ---- x ----
        const int t = c >> 10, q = c & 1023;
        const int row = q >> 3, kc = q & 7;
        const int rb = t >> 2, kb = t & 3;
        const float* s = x + (size_t)(rb * 128 + row) * D_K + kb * 64 + kc * 8;
        short8_t o;
#pragma unroll
        for (int j = 0; j < 8; ++j) o[j] = (short)f2bf(s[j]);
        *reinterpret_cast<short8_t*>(xs + (size_t)t * 8192 + SWZ(row, kc)) = o;
    } else if (c < 393216) {                // ---- h0 ----
        const int c2 = c - 131072;
        const int t = c2 >> 10, q = c2 & 1023;
        const int row = q >> 3, kc = q & 7;
        const int rb = t >> 3, kb = t & 7;
        const float* s = h0 + (size_t)(rb * 128 + row) * U_N + kb * 64 + kc * 8;
        short8_t o;
#pragma unroll
        for (int j = 0; j < 8; ++j) o[j] = (short)f2bf(s[j]);
        *reinterpret_cast<short8_t*>(hs + (size_t)t * 8192 + SWZ(row, kc)) = o;
    } else if (c < 475136) {                // ---- kernel (transpose) ----
        const int c2 = c - 393216;
        const int t = c2 / 1280, q = c2 - t * 1280;
        const int kc = q / 160, r = q - kc * 160;     // r = mat*32 + cc
        const int nb = t >> 2, kb = t & 3;
        const int col = (r >> 5) * U_N + nb * 32 + (r & 31);
        short8_t o;
#pragma unroll
        for (int j = 0; j < 8; ++j)
            o[j] = (short)f2bf(kern[(size_t)(kb * 64 + kc * 8 + j) * 2560 + col]);
        *reinterpret_cast<short8_t*>(ksw + (size_t)t * 10240 + SWZ(r, kc)) = o;
    } else {                                // ---- rk (transpose) ----
        const int c2 = c - 475136;
        const int t = c2 / 768, q = c2 - t * 768;
        const int kc = q / 96, r = q - kc * 96;       // r = mat*32 + cc
        const int nb = t >> 3, kb = t & 7;
        const int col = (r >> 5) * U_N + nb * 32 + (r & 31);
        short8_t o;
#pragma unroll
        for (int j = 0; j < 8; ++j)
            o[j] = (short)f2bf(rk[(size_t)(kb * 64 + kc * 8 + j) * 1536 + col]);
        *reinterpret_cast<short8_t*>(rsw + (size_t)t * 6144 + SWZ(r, kc)) = o;
    }
}

// ---------------------------------------------------------------------------
// main fused kernel
// grid (8, 32) = 256 blocks (1/CU), 512 threads (8 waves, 2/SIMD)
// wave (wm, wn) = (wave>>2, wave&3): rows [64*wm,+64) x cols [16*wn,+16)
// of the 128x64 band, for every stacked gate matrix.
// B in LDS = two 32-col prep tiles stacked: phase1 2x160 rows, phase2 2x96.
// ---------------------------------------------------------------------------
__global__ __launch_bounds__(512, 2) void tlstm_main(
    const unsigned short* __restrict__ xs,    // swizzled x tiles
    const unsigned short* __restrict__ hs,    // swizzled h0 tiles
    const unsigned short* __restrict__ ksw,   // swizzled kernel^T tiles
    const unsigned short* __restrict__ rsw,   // swizzled rk^T tiles
    const float* __restrict__ tvec,           // [4096]
    const float* __restrict__ c0,             // [4096][512]
    const float* __restrict__ ktime,          // [1536] cols [t1,t2,o]
    float* __restrict__ out)                  // h, then c_m
{
    // per buffer: A 8192 elems (16KB) + B 20480 elems (40KB) = 56KB; x2 = 112KB
    __shared__ __align__(16) unsigned short lds[2][28672];

    const int tid = threadIdx.x;
    const int wave = tid >> 6;
    const int lane = tid & 63;
    const int lr = lane & 15;
    const int lq = lane >> 4;
    const int wm = wave >> 2;                 // 0..1 : 64-row half
    const int wn = wave & 3;                  // 0..3 : 16-col slice
    const int nb = blockIdx.x;                // 0..7  (64-col blocks)
    const int rb = blockIdx.y;                // 0..31 (128-row blocks)

    const int u = nb * 64 + wn * 16 + lr;     // output column

    // acc[m][p]: gate m (0..4 = x@K, 5..7 = h0@RK), row frag p (wm*64+p*16)
    f32x4_t acc[8][4];
#pragma unroll
    for (int m = 0; m < 8; ++m)
#pragma unroll
        for (int p = 0; p < 4; ++p)
            acc[m][p] = (f32x4_t){0.f, 0.f, 0.f, 0.f};

    float c0r[16];                            // c0 prefetch (filled at step 8)

    // ---- staging: linear global_load_lds, wave-uniform LDS dest ----
    // per-thread vmem ops: phase1 (s<4): 2 A + 5 B = 7; phase2: 2 A + 3 B = 5
    auto stage = [&](int s, int buf) {
        unsigned short* ab = &lds[buf][0];
        unsigned short* bb = &lds[buf][8192];
        if (s < 4) {
            const unsigned short* at = xs + (size_t)(rb * 4 + s) * 8192;
            gl16(at + (size_t)tid * 8,         ab + (size_t)(wave * 64) * 8);
            gl16(at + (size_t)(512 + tid) * 8, ab + (size_t)(512 + wave * 64) * 8);
            const unsigned short* b0 = ksw + (size_t)(nb * 8 + s) * 10240;
            const unsigned short* b1 = ksw + (size_t)(nb * 8 + 4 + s) * 10240;
#pragma unroll
            for (int j = 0; j < 5; ++j) {
                const int c = j * 512 + tid;            // 0..2559; 1280 wave-aligned
                const unsigned short* src = (c < 1280) ? (b0 + (size_t)c * 8)
                                                       : (b1 + (size_t)(c - 1280) * 8);
                gl16(src, bb + (size_t)(j * 512 + wave * 64) * 8);
            }
        } else {
            const unsigned short* at = hs + (size_t)(rb * 8 + (s - 4)) * 8192;
            gl16(at + (size_t)tid * 8,         ab + (size_t)(wave * 64) * 8);
            gl16(at + (size_t)(512 + tid) * 8, ab + (size_t)(512 + wave * 64) * 8);
            const unsigned short* b0 = rsw + (size_t)(nb * 16 + (s - 4)) * 6144;
            const unsigned short* b1 = rsw + (size_t)(nb * 16 + 8 + (s - 4)) * 6144;
#pragma unroll
            for (int j = 0; j < 3; ++j) {
                const int c = j * 512 + tid;            // 0..1535; 768 wave-aligned
                const unsigned short* src = (c < 768) ? (b0 + (size_t)c * 8)
                                                      : (b1 + (size_t)(c - 768) * 8);
                gl16(src, bb + (size_t)(j * 512 + wave * 64) * 8);
            }
        }
    };

    auto compute1 = [&](int buf) {      // x @ kernel -> acc[0..4]
        const unsigned short* ab = &lds[buf][0];
        const unsigned short* bb = &lds[buf][8192];
#pragma unroll
        for (int ks = 0; ks < 2; ++ks) {
            const int kc = ks * 4 + lq;
            short8_t a[4];
#pragma unroll
            for (int p = 0; p < 4; ++p)
                a[p] = *reinterpret_cast<const short8_t*>(ab + SWZ(wm * 64 + p * 16 + lr, kc));
#pragma unroll
            for (int m = 0; m < 5; ++m) {
                const int r = (wn >> 1) * 160 + m * 32 + (wn & 1) * 16 + lr;
                short8_t b = *reinterpret_cast<const short8_t*>(bb + SWZ(r, kc));
#pragma unroll
                for (int p = 0; p < 4; ++p)
                    acc[m][p] = __builtin_amdgcn_mfma_f32_16x16x32_bf16(a[p], b, acc[m][p], 0, 0, 0);
            }
        }
    };

    auto compute2 = [&](int buf) {      // h0 @ rk -> acc[5..7]
        const unsigned short* ab = &lds[buf][0];
        const unsigned short* bb = &lds[buf][8192];
#pragma unroll
        for (int ks = 0; ks < 2; ++ks) {
            const int kc = ks * 4 + lq;
            short8_t a[4];
#pragma unroll
            for (int p = 0; p < 4; ++p)
                a[p] = *reinterpret_cast<const short8_t*>(ab + SWZ(wm * 64 + p * 16 + lr, kc));
#pragma unroll
            for (int m = 0; m < 3; ++m) {
                const int r = (wn >> 1) * 96 + m * 32 + (wn & 1) * 16 + lr;
                short8_t b = *reinterpret_cast<const short8_t*>(bb + SWZ(r, kc));
#pragma unroll
                for (int p = 0; p < 4; ++p)
                    acc[5 + m][p] = __builtin_amdgcn_mfma_f32_16x16x32_bf16(a[p], b, acc[5 + m][p], 0, 0, 0);
            }
        }
    };

    // step body: wait for tile S (leave NV younger ops in flight), barrier,
    // compute, barrier (protects buffer S&1 from being overwritten by
    // stage(S+2) in the next step before all waves finished reading it).
#define K_BODY(S, NV, CF)                                  \
    {                                                      \
        WAIT_VM(NV);                                       \
        __builtin_amdgcn_s_barrier();                      \
        __builtin_amdgcn_sched_barrier(0);                 \
        CF((S) & 1);                                       \
        __builtin_amdgcn_sched_barrier(0);                 \
        __builtin_amdgcn_s_barrier();                      \
        __builtin_amdgcn_sched_barrier(0);                 \
    }

    // ---- counted-vmcnt pipelined K-loop: 12 steps ----
    // per-wave vmem FIFO: L = [7,7,7,7,5,5,5,5,5,5,5,5]; c0 (16 ops) at s8.
    stage(0, 0);
    stage(1, 1);  K_BODY(0, 7,  compute1);
    stage(2, 0);  K_BODY(1, 7,  compute1);
    stage(3, 1);  K_BODY(2, 7,  compute1);
    stage(4, 0);  K_BODY(3, 5,  compute1);
    stage(5, 1);  K_BODY(4, 5,  compute2);
    stage(6, 0);  K_BODY(5, 5,  compute2);
    stage(7, 1);  K_BODY(6, 5,  compute2);
    stage(8, 0);  K_BODY(7, 5,  compute2);
    stage(9, 1);
    asm volatile("" ::: "memory");   // pin c0 loads after stage(9) in the FIFO
#pragma unroll
    for (int p = 0; p < 4; ++p)
#pragma unroll
        for (int i2 = 0; i2 < 4; ++i2) {
            const int b = rb * 128 + wm * 64 + p * 16 + lq * 4 + i2;
            c0r[p * 4 + i2] = c0[(size_t)b * U_N + u];
        }
    K_BODY(8, 21, compute2);         // leave t9(5) + c0(16) in flight
    stage(10, 0); K_BODY(9, 21, compute2);   // leave c0(16) + t10(5)
    stage(11, 1); K_BODY(10, 5, compute2);   // c0+t10 retired; leave t11(5)
    K_BODY(11, 0, compute2);

    // ---- epilogue: TimeLSTM elementwise (fp32) ----
    const float NEG_EPS = -1e-5f;
    const float kt1 = ktime[u];
    const float kt2 = ktime[U_N + u];
    const float kto = ktime[2 * U_N + u];
#pragma unroll
    for (int p = 0; p < 4; ++p)
#pragma unroll
        for (int i2 = 0; i2 < 4; ++i2) {
            const int b = rb * 128 + wm * 64 + p * 16 + lq * 4 + i2;
            const float tb = tvec[b];
            const float c0v = c0r[p * 4 + i2];
            const float x_i  = acc[0][p][i2];
            const float x_c  = acc[1][p][i2];
            const float x_o  = acc[2][p][i2];
            const float x_t1 = acc[3][p][i2];
            const float x_t2 = acc[4][p][i2];
            const float r_i  = acc[5][p][i2];
            const float r_c  = acc[6][p][i2];
            const float r_o  = acc[7][p][i2];

            const float ig  = sigf(x_i + r_i);
            const float t1v = sigf(x_t1 + sigf(tb * kt1));
            const float t1c = (t1v > NEG_EPS) ? NEG_EPS : t1v;
            const float t2v = sigf(x_t2 + sigf(tb * kt2));
            const float ct  = tanhfast(x_c + r_c);
            const float cm_ = (1.f - ig * t1v) * c0v + ig * ct * t1c;
            const float cm  = (1.f - ig) * c0v + ig * ct * t2v;
            const float og  = sigf(x_o + r_o + tb * kto);

            out[(size_t)b * U_N + u] = tanhfast(cm_) * og;
            out[(size_t)B_N * U_N + (size_t)b * U_N + u] = cm;
        }
}

// ---------------------------------------------------------------------------
extern "C" void kernel_launch(void* const* d_in, const int* in_sizes, int n_in,
                              void* d_out, int out_size, void* d_ws, size_t ws_size,
                              hipStream_t stream) {
    const float* x     = (const float*)d_in[0];   // [4096][256]
    const float* t     = (const float*)d_in[1];   // [4096][1]
    const float* h0    = (const float*)d_in[2];   // [4096][512]
    const float* c0    = (const float*)d_in[3];   // [4096][512]
    const float* kern  = (const float*)d_in[4];   // [256][2560]
    const float* rk    = (const float*)d_in[5];   // [512][1536]
    const float* ktime = (const float*)d_in[6];   // [1][1536]
    float* out = (float*)d_out;

    // ws layout (bytes):
    //   xs  @ 0        : 4096*256*2  = 2,097,152  (swizzled 128x64 tiles)
    //   hs  @ 2097152  : 4096*512*2  = 4,194,304
    //   ksw @ 6291456  : 2560*256*2  = 1,310,720  (swizzled 160x64 tiles)
    //   rsw @ 7602176  : 1536*512*2  = 1,572,864  (swizzled  96x64 tiles)
    unsigned short* xs  = (unsigned short*)d_ws;
    unsigned short* hs  = (unsigned short*)((char*)d_ws + 2097152);
    unsigned short* ksw = (unsigned short*)((char*)d_ws + 6291456);
    unsigned short* rsw = (unsigned short*)((char*)d_ws + 7602176);

    prep<<<2240, 256, 0, stream>>>(x, h0, kern, rk, xs, hs, ksw, rsw);
    tlstm_main<<<dim3(8, 32), 512, 0, stream>>>(
        xs, hs, ksw, rsw, t, c0, ktime, out);
}

// Round 4
// 32.725 us; speedup vs baseline: 1.0938x; 1.0938x over previous
//
#include <hip/hip_runtime.h>

// ---------------------------------------------------------------------------
// TimeLSTMCell fused kernel for MI355X (gfx950) — round 6
// B=4096, D=256, U=512; out = concat(h, c_m) fp32
//
// prep kernel (UNCHANGED): x,h0 -> bf16 swizzled 128x64 tiles; kernel,rk ->
//   transposed bf16 swizzled {160,96}x64 tiles. Main kernel stages with
//   linear global_load_lds and reads with the XOR swizzle.
//
// ROUND 6: exactly the round-4 kernel (128x32 tile, 4 waves 2x2, 72KB LDS,
//   2 blocks/CU — the best measured config, 33.2us) with ONE change:
//   __syncthreads per K-step -> counted-vmcnt step:
//     stage(s+1); s_waitcnt vmcnt(L(s+1)); s_barrier; compute(s); s_barrier
//   L = loads/thread of the just-issued tile (9 phase1 / 7 phase2), so the
//   wait only requires tile s to have landed — tile s+1 stays in flight
//   across the whole step (T3/T4, m218). r5 bundled this with a tile
//   widening that dropped to 1 block/CU and regressed; this round keeps the
//   2 independent blocks/CU AND adds the slack.
// ---------------------------------------------------------------------------

typedef __attribute__((ext_vector_type(8))) short short8_t;   // 8 bf16
typedef __attribute__((ext_vector_type(4))) float f32x4_t;
typedef unsigned int u32;

#define B_N 4096
#define D_K 256
#define U_N 512

__device__ __forceinline__ unsigned short f2bf(float f) {
    unsigned int x = __float_as_uint(f);
    unsigned int r = x + 0x7fffu + ((x >> 16) & 1u);   // RNE
    return (unsigned short)(r >> 16);
}

__device__ __forceinline__ float sigf(float z) {
    return 1.0f / (1.0f + __expf(-z));
}

// fast tanh: exact at +/-inf, ~1e-7 abs err
__device__ __forceinline__ float tanhfast(float z) {
    return 1.0f - 2.0f / (1.0f + __expf(2.0f * z));
}

__device__ __forceinline__ void gl16(const unsigned short* g, unsigned short* l) {
    __builtin_amdgcn_global_load_lds(
        (const __attribute__((address_space(1))) u32*)g,
        (__attribute__((address_space(3))) u32*)l, 16, 0, 0);
}

// swizzled element offset of (row r, k-chunk kc) inside a tile with 8 chunks/row
#define SWZ(r, kc) ((((r) * 8) + ((kc) ^ ((r) & 7))) * 8)

// counted vmcnt wait + scheduling fence (compile-time literal N)
#define WAIT_VM(N)                                            \
    asm volatile("s_waitcnt vmcnt(" #N ")" ::: "memory");     \
    __builtin_amdgcn_sched_barrier(0)

// ---------------------------------------------------------------------------
// prepass (unchanged): 4 segments by flat chunk id (16B bf16 chunk each)
// ---------------------------------------------------------------------------
__global__ __launch_bounds__(256) void prep(
    const float* __restrict__ x, const float* __restrict__ h0,
    const float* __restrict__ kern, const float* __restrict__ rk,
    unsigned short* __restrict__ xs, unsigned short* __restrict__ hs,
    unsigned short* __restrict__ ksw, unsigned short* __restrict__ rsw)
{
    const int c = blockIdx.x * 256 + threadIdx.x;
    if (c < 131072) {                       // ---- x ----
        const int t = c >> 10, q = c & 1023;
        const int row = q >> 3, kc = q & 7;
        const int rb = t >> 2, kb = t & 3;
        const float* s = x + (size_t)(rb * 128 + row) * D_K + kb * 64 + kc * 8;
        short8_t o;
#pragma unroll
        for (int j = 0; j < 8; ++j) o[j] = (short)f2bf(s[j]);
        *reinterpret_cast<short8_t*>(xs + (size_t)t * 8192 + SWZ(row, kc)) = o;
    } else if (c < 393216) {                // ---- h0 ----
        const int c2 = c - 131072;
        const int t = c2 >> 10, q = c2 & 1023;
        const int row = q >> 3, kc = q & 7;
        const int rb = t >> 3, kb = t & 7;
        const float* s = h0 + (size_t)(rb * 128 + row) * U_N + kb * 64 + kc * 8;
        short8_t o;
#pragma unroll
        for (int j = 0; j < 8; ++j) o[j] = (short)f2bf(s[j]);
        *reinterpret_cast<short8_t*>(hs + (size_t)t * 8192 + SWZ(row, kc)) = o;
    } else if (c < 475136) {                // ---- kernel (transpose) ----
        const int c2 = c - 393216;
        const int t = c2 / 1280, q = c2 - t * 1280;
        const int kc = q / 160, r = q - kc * 160;     // r = mat*32 + cc
        const int nb = t >> 2, kb = t & 3;
        const int col = (r >> 5) * U_N + nb * 32 + (r & 31);
        short8_t o;
#pragma unroll
        for (int j = 0; j < 8; ++j)
            o[j] = (short)f2bf(kern[(size_t)(kb * 64 + kc * 8 + j) * 2560 + col]);
        *reinterpret_cast<short8_t*>(ksw + (size_t)t * 10240 + SWZ(r, kc)) = o;
    } else {                                // ---- rk (transpose) ----
        const int c2 = c - 475136;
        const int t = c2 / 768, q = c2 - t * 768;
        const int kc = q / 96, r = q - kc * 96;       // r = mat*32 + cc
        const int nb = t >> 3, kb = t & 7;
        const int col = (r >> 5) * U_N + nb * 32 + (r & 31);
        short8_t o;
#pragma unroll
        for (int j = 0; j < 8; ++j)
            o[j] = (short)f2bf(rk[(size_t)(kb * 64 + kc * 8 + j) * 1536 + col]);
        *reinterpret_cast<short8_t*>(rsw + (size_t)t * 6144 + SWZ(r, kc)) = o;
    }
}

// ---------------------------------------------------------------------------
// main fused kernel
// grid (16, 32) = 512 blocks (2/CU), 256 threads (4 waves)
// wave (wm,wn) = (wave>>1, wave&1) owns rows [64*wm, 64*wm+64) x cols
// [16*wn, 16*wn+16) of the 128x32 band, for every stacked gate matrix.
// ---------------------------------------------------------------------------
__global__ __launch_bounds__(256, 2) void tlstm_main(
    const unsigned short* __restrict__ xs,    // swizzled x tiles
    const unsigned short* __restrict__ hs,    // swizzled h0 tiles
    const unsigned short* __restrict__ ksw,   // swizzled kernel^T tiles
    const unsigned short* __restrict__ rsw,   // swizzled rk^T tiles
    const float* __restrict__ tvec,           // [4096]
    const float* __restrict__ c0,             // [4096][512]
    const float* __restrict__ ktime,          // [1536] cols [t1,t2,o]
    float* __restrict__ out)                  // h, then c_m
{
    // per buffer: A 8192 elems (16KB) + B 10240 elems (20KB) = 36KB; x2 = 72KB
    __shared__ __align__(16) unsigned short lds[2][18432];

    const int tid = threadIdx.x;
    const int wave = tid >> 6;
    const int lane = tid & 63;
    const int lr = lane & 15;
    const int lq = lane >> 4;
    const int wm = wave >> 1;                 // 0..1 : row half
    const int wn = wave & 1;                  // 0..1 : col half
    const int nb = blockIdx.x;
    const int rb = blockIdx.y;

    // acc[m][p]: gate matrix m (0..4 = x@K gates, 5..7 = h0@RK gates),
    // row-fragment p (rows wm*64 + p*16), cols wn*16..+16
    f32x4_t acc[8][4];
#pragma unroll
    for (int m = 0; m < 8; ++m)
#pragma unroll
        for (int p = 0; p < 4; ++p)
            acc[m][p] = (f32x4_t){0.f, 0.f, 0.f, 0.f};

    // ---- staging: linear global_load_lds, wave-uniform LDS dest ----
    // per-thread vmem ops: phase1 (s<4): 4 A + 5 B = 9; phase2: 4 A + 3 B = 7
    auto stage = [&](int s, int buf) {
        unsigned short* ab = &lds[buf][0];
        unsigned short* bb = &lds[buf][8192];
        if (s < 4) {
            const unsigned short* at = xs + (size_t)(rb * 4 + s) * 8192;
#pragma unroll
            for (int j = 0; j < 4; ++j)
                gl16(at + (j * 256 + tid) * 8, ab + (j * 256 + wave * 64) * 8);
            const unsigned short* bt = ksw + (size_t)(nb * 4 + s) * 10240;
#pragma unroll
            for (int j = 0; j < 5; ++j)
                gl16(bt + (j * 256 + tid) * 8, bb + (j * 256 + wave * 64) * 8);
        } else {
            const unsigned short* at = hs + (size_t)(rb * 8 + (s - 4)) * 8192;
#pragma unroll
            for (int j = 0; j < 4; ++j)
                gl16(at + (j * 256 + tid) * 8, ab + (j * 256 + wave * 64) * 8);
            const unsigned short* bt = rsw + (size_t)(nb * 8 + (s - 4)) * 6144;
#pragma unroll
            for (int j = 0; j < 3; ++j)
                gl16(bt + (j * 256 + tid) * 8, bb + (j * 256 + wave * 64) * 8);
        }
    };

    auto compute1 = [&](int buf) {      // x @ kernel -> acc[0..4]
        const unsigned short* ab = &lds[buf][0];
        const unsigned short* bb = &lds[buf][8192];
#pragma unroll
        for (int ks = 0; ks < 2; ++ks) {
            const int kc = ks * 4 + lq;
            short8_t a[4];
#pragma unroll
            for (int p = 0; p < 4; ++p)
                a[p] = *reinterpret_cast<const short8_t*>(ab + SWZ(wm * 64 + p * 16 + lr, kc));
#pragma unroll
            for (int m = 0; m < 5; ++m) {
                const int r = m * 32 + wn * 16 + lr;
                short8_t b = *reinterpret_cast<const short8_t*>(bb + SWZ(r, kc));
#pragma unroll
                for (int p = 0; p < 4; ++p)
                    acc[m][p] = __builtin_amdgcn_mfma_f32_16x16x32_bf16(a[p], b, acc[m][p], 0, 0, 0);
            }
        }
    };

    auto compute2 = [&](int buf) {      // h0 @ rk -> acc[5..7]
        const unsigned short* ab = &lds[buf][0];
        const unsigned short* bb = &lds[buf][8192];
#pragma unroll
        for (int ks = 0; ks < 2; ++ks) {
            const int kc = ks * 4 + lq;
            short8_t a[4];
#pragma unroll
            for (int p = 0; p < 4; ++p)
                a[p] = *reinterpret_cast<const short8_t*>(ab + SWZ(wm * 64 + p * 16 + lr, kc));
#pragma unroll
            for (int m = 0; m < 3; ++m) {
                const int r = m * 32 + wn * 16 + lr;
                short8_t b = *reinterpret_cast<const short8_t*>(bb + SWZ(r, kc));
#pragma unroll
                for (int p = 0; p < 4; ++p)
                    acc[5 + m][p] = __builtin_amdgcn_mfma_f32_16x16x32_bf16(a[p], b, acc[5 + m][p], 0, 0, 0);
            }
        }
    };

    // step body for tile S: wait until tile S's loads landed (leave the NV
    // just-issued loads of tile S+1 in flight), sync, compute, sync (the
    // trailing barrier keeps stage(S+2) from overwriting buffer S&1 while
    // another wave still reads it).
#define K_BODY(S, NV, CF)                                  \
    {                                                      \
        WAIT_VM(NV);                                       \
        __builtin_amdgcn_s_barrier();                      \
        __builtin_amdgcn_sched_barrier(0);                 \
        CF((S) & 1);                                       \
        __builtin_amdgcn_sched_barrier(0);                 \
        __builtin_amdgcn_s_barrier();                      \
        __builtin_amdgcn_sched_barrier(0);                 \
    }

    // ---- counted-vmcnt pipelined K-loop: 12 steps ----
    // per-thread load counts: L = [9,9,9,9,7,7,7,7,7,7,7,7]
    stage(0, 0);
    stage(1, 1);   K_BODY(0, 9, compute1);
    stage(2, 0);   K_BODY(1, 9, compute1);
    stage(3, 1);   K_BODY(2, 9, compute1);
    stage(4, 0);   K_BODY(3, 7, compute1);
    stage(5, 1);   K_BODY(4, 7, compute2);
    stage(6, 0);   K_BODY(5, 7, compute2);
    stage(7, 1);   K_BODY(6, 7, compute2);
    stage(8, 0);   K_BODY(7, 7, compute2);
    stage(9, 1);   K_BODY(8, 7, compute2);
    stage(10, 0);  K_BODY(9, 7, compute2);
    stage(11, 1);  K_BODY(10, 7, compute2);
    K_BODY(11, 0, compute2);

    // ---- epilogue: TimeLSTM elementwise (fp32) ----
    const float NEG_EPS = -1e-5f;
    const int u = nb * 32 + wn * 16 + lr;
    const float kt1 = ktime[u];
    const float kt2 = ktime[U_N + u];
    const float kto = ktime[2 * U_N + u];
#pragma unroll
    for (int p = 0; p < 4; ++p)
#pragma unroll
        for (int i2 = 0; i2 < 4; ++i2) {
            const int b = rb * 128 + wm * 64 + p * 16 + lq * 4 + i2;
            const float tb = tvec[b];
            const float c0v = c0[(size_t)b * U_N + u];
            const float x_i  = acc[0][p][i2];
            const float x_c  = acc[1][p][i2];
            const float x_o  = acc[2][p][i2];
            const float x_t1 = acc[3][p][i2];
            const float x_t2 = acc[4][p][i2];
            const float r_i  = acc[5][p][i2];
            const float r_c  = acc[6][p][i2];
            const float r_o  = acc[7][p][i2];

            const float ig  = sigf(x_i + r_i);
            const float t1v = sigf(x_t1 + sigf(tb * kt1));
            const float t1c = (t1v > NEG_EPS) ? NEG_EPS : t1v;
            const float t2v = sigf(x_t2 + sigf(tb * kt2));
            const float ct  = tanhfast(x_c + r_c);
            const float cm_ = (1.f - ig * t1v) * c0v + ig * ct * t1c;
            const float cm  = (1.f - ig) * c0v + ig * ct * t2v;
            const float og  = sigf(x_o + r_o + tb * kto);

            out[(size_t)b * U_N + u] = tanhfast(cm_) * og;
            out[(size_t)B_N * U_N + (size_t)b * U_N + u] = cm;
        }
}

// ---------------------------------------------------------------------------
extern "C" void kernel_launch(void* const* d_in, const int* in_sizes, int n_in,
                              void* d_out, int out_size, void* d_ws, size_t ws_size,
                              hipStream_t stream) {
    const float* x     = (const float*)d_in[0];   // [4096][256]
    const float* t     = (const float*)d_in[1];   // [4096][1]
    const float* h0    = (const float*)d_in[2];   // [4096][512]
    const float* c0    = (const float*)d_in[3];   // [4096][512]
    const float* kern  = (const float*)d_in[4];   // [256][2560]
    const float* rk    = (const float*)d_in[5];   // [512][1536]
    const float* ktime = (const float*)d_in[6];   // [1][1536]
    float* out = (float*)d_out;

    // ws layout (bytes):
    //   xs  @ 0        : 4096*256*2  = 2,097,152  (swizzled 128x64 tiles)
    //   hs  @ 2097152  : 4096*512*2  = 4,194,304
    //   ksw @ 6291456  : 2560*256*2  = 1,310,720  (swizzled 160x64 tiles)
    //   rsw @ 7602176  : 1536*512*2  = 1,572,864  (swizzled  96x64 tiles)
    unsigned short* xs  = (unsigned short*)d_ws;
    unsigned short* hs  = (unsigned short*)((char*)d_ws + 2097152);
    unsigned short* ksw = (unsigned short*)((char*)d_ws + 6291456);
    unsigned short* rsw = (unsigned short*)((char*)d_ws + 7602176);

    prep<<<2240, 256, 0, stream>>>(x, h0, kern, rk, xs, hs, ksw, rsw);
    tlstm_main<<<dim3(16, 32), 256, 0, stream>>>(
        xs, hs, ksw, rsw, t, c0, ktime, out);
}